// Round 1
// baseline (780.861 us; speedup 1.0000x reference)
//
#include <hip/hip_runtime.h>

#define S_LEN 8192
#define C_CTX 21
#define E_DIM 128
#define G_DIM 36
#define H_DIM 1024
#define T_TAG 32
#define D_RAW 3444          // 21*(128+36)
#define DP 3456             // padded to multiple of 32 (108 K-iters)
#define START_TAG 30
#define STOP_TAG 31
#define NEGV -10000.0f
#define K_CHUNKS 64
#define L_CHUNK 128         // K_CHUNKS * L_CHUNK == S_LEN

typedef __bf16 bf16_t;
typedef __bf16 bf16x8 __attribute__((ext_vector_type(8)));
typedef float  f32x4  __attribute__((ext_vector_type(4)));

__device__ inline void async_copy16(const bf16_t* g, bf16_t* l) {
    __builtin_amdgcn_global_load_lds(
        (const __attribute__((address_space(1))) void*)g,
        (__attribute__((address_space(3))) void*)l, 16, 0, 0);
}

// ---------------- Phase 0: materialize padded bf16 X and W1 ----------------
__global__ void build_x(const int* __restrict__ ctx, const float* __restrict__ gz,
                        const float* __restrict__ emb, bf16_t* __restrict__ X) {
    const int s = blockIdx.x;
    for (int col = threadIdx.x; col < DP; col += 256) {
        float v = 0.f;
        if (col < D_RAW) {
            const int c = col / 164;
            const int r = col - c * 164;
            if (r < E_DIM) v = emb[(size_t)ctx[s * C_CTX + c] * E_DIM + r];
            else           v = gz[((size_t)s * C_CTX + c) * G_DIM + (r - E_DIM)];
        }
        X[(size_t)s * DP + col] = (bf16_t)v;
    }
}

__global__ void build_w1b(const float* __restrict__ w1, bf16_t* __restrict__ W) {
    const int h = blockIdx.x;
    for (int col = threadIdx.x; col < DP; col += 256)
        W[(size_t)h * DP + col] = (bf16_t)((col < D_RAW) ? w1[(size_t)h * D_RAW + col] : 0.f);
}

// ---------------- Phase 1: h = relu(X @ W1^T + b1), bf16 MFMA -------------
// 128x128 tile, 4 waves, each wave 64x64 (4x4 of 16x16x32 MFMA). m97 structure.
__global__ __launch_bounds__(256) void gemm1(const bf16_t* __restrict__ X,
                                             const bf16_t* __restrict__ W,
                                             const float* __restrict__ b1,
                                             bf16_t* __restrict__ Hout) {
    __shared__ bf16_t As[128 * 32];
    __shared__ bf16_t Bs[128 * 32];
    const int tid  = threadIdx.x;
    const int wave = tid >> 6, lane = tid & 63;
    const int s0 = blockIdx.x * 128, h0 = blockIdx.y * 128;
    const int wm = (wave & 1) * 64, wn = (wave >> 1) * 64;

    // staging: thread t handles 8 bf16 (16B) at linear chunk t and t+256
    const int rowA = tid >> 2, colA = (tid & 3) * 8;
    const bf16_t* gA0 = X + (size_t)(s0 + rowA) * DP + colA;
    const bf16_t* gA1 = X + (size_t)(s0 + rowA + 64) * DP + colA;
    const bf16_t* gB0 = W + (size_t)(h0 + rowA) * DP + colA;
    const bf16_t* gB1 = W + (size_t)(h0 + rowA + 64) * DP + colA;
    bf16_t* lA0 = &As[tid * 8];
    bf16_t* lA1 = &As[(tid + 256) * 8];
    bf16_t* lB0 = &Bs[tid * 8];
    bf16_t* lB1 = &Bs[(tid + 256) * 8];

    const int lrow = lane & 15;
    const int kq   = (lane >> 4) * 8;

    f32x4 acc[4][4] = {};
    for (int k0 = 0; k0 < DP; k0 += 32) {
        async_copy16(gA0 + k0, lA0);
        async_copy16(gA1 + k0, lA1);
        async_copy16(gB0 + k0, lB0);
        async_copy16(gB1 + k0, lB1);
        __syncthreads();   // compiler emits vmcnt(0) drain before barrier
        bf16x8 a[4], b[4];
#pragma unroll
        for (int mt = 0; mt < 4; ++mt)
            a[mt] = *(const bf16x8*)&As[(wm + mt * 16 + lrow) * 32 + kq];
#pragma unroll
        for (int nt = 0; nt < 4; ++nt)
            b[nt] = *(const bf16x8*)&Bs[(wn + nt * 16 + lrow) * 32 + kq];
#pragma unroll
        for (int mt = 0; mt < 4; ++mt)
#pragma unroll
            for (int nt = 0; nt < 4; ++nt)
                acc[mt][nt] = __builtin_amdgcn_mfma_f32_16x16x32_bf16(a[mt], b[nt], acc[mt][nt], 0, 0, 0);
        __syncthreads();
    }
    // epilogue: C/D layout col=lane&15, row=(lane>>4)*4+reg
    const int crow = (lane >> 4) * 4;
    const int ccol = lane & 15;
#pragma unroll
    for (int nt = 0; nt < 4; ++nt) {
        const int j = h0 + wn + nt * 16 + ccol;
        const float bv = b1[j];
#pragma unroll
        for (int mt = 0; mt < 4; ++mt) {
#pragma unroll
            for (int r = 0; r < 4; ++r) {
                const int s = s0 + wm + mt * 16 + crow + r;
                const float v = acc[mt][nt][r] + bv;
                Hout[(size_t)s * H_DIM + j] = (bf16_t)fmaxf(v, 0.f);
            }
        }
    }
}

// ---------------- Phase 2: feats = h @ w2^T + b2 (fp32 out) ----------------
__global__ void feats_k(const bf16_t* __restrict__ Hb, const float* __restrict__ w2,
                        const float* __restrict__ b2, float* __restrict__ F) {
    const int t  = threadIdx.x;             // 0..31
    const int sl = threadIdx.y;             // 0..7
    const int s  = blockIdx.x * 8 + sl;
    const bf16_t* hr = Hb + (size_t)s * H_DIM;
    const float*  wr = w2 + t * H_DIM;
    float acc = b2[t];
    for (int j = 0; j < H_DIM; j += 8) {
        bf16x8 hv = *(const bf16x8*)(hr + j);
#pragma unroll
        for (int u = 0; u < 8; ++u) acc += (float)hv[u] * wr[j + u];
    }
    F[(size_t)s * T_TAG + t] = acc;
}

// ---------------- Gold score (one block) ----------------
__global__ void gold_k(const float* __restrict__ F, const int* __restrict__ lab,
                       const float* __restrict__ trans, float* __restrict__ gold) {
    __shared__ float red[4];
    const int tid = threadIdx.x;
    float acc = 0.f;
    for (int s = tid; s < S_LEN; s += 256) {
        const int t = lab[s];
        acc += F[(size_t)s * T_TAG + t];
        const int tp = (s == 0) ? START_TAG : lab[s - 1];
        acc += trans[t * T_TAG + tp];
    }
    if (tid == 0) acc += trans[STOP_TAG * T_TAG + lab[S_LEN - 1]];
#pragma unroll
    for (int off = 32; off; off >>= 1) acc += __shfl_down(acc, off, 64);
    if ((tid & 63) == 0) red[tid >> 6] = acc;
    __syncthreads();
    if (tid == 0) gold[0] = red[0] + red[1] + red[2] + red[3];
}

// ---------------- CRF pass A: per-chunk matrix-chain products --------------
// chunk c: P_c = M_{s0+L-1} ... M_{s0}, M_s[n,p] = exp(trans[n,p]+feat_s[n]).
// One 32-lane group owns one column p (lane = n). Per-column log-scale sigma.
// Stored transposed: QT[c][p][n] = P_c[n][p] * exp(-sigma[c][p]).
__global__ __launch_bounds__(256) void crfA(const float* __restrict__ F,
                                            const float* __restrict__ trans,
                                            float* __restrict__ QT,
                                            float* __restrict__ sigma) {
    __shared__ float fl[L_CHUNK * 32];
    const int c   = blockIdx.x >> 2;
    const int tid = threadIdx.x;
    const int n   = tid & 31;
    const int p   = ((blockIdx.x & 3) << 3) + (tid >> 5);
    const int s0  = c * L_CHUNK;
    for (int i = tid; i < L_CHUNK * 32; i += 256) fl[i] = F[(size_t)s0 * 32 + i];
    __syncthreads();

    float et[32];
#pragma unroll
    for (int k = 0; k < 32; ++k) et[k] = __expf(trans[n * 32 + k]);

    float v  = __expf(trans[n * 32 + p] + fl[n]);   // first matrix, column p
    float sg = 0.f;
    for (int s = 1; s < L_CHUNK; ++s) {
        const float ef = __expf(fl[s * 32 + n]);
        float a0 = 0.f, a1 = 0.f, a2 = 0.f, a3 = 0.f;
#pragma unroll
        for (int k = 0; k < 32; k += 4) {
            a0 += et[k + 0] * __shfl(v, k + 0, 32);
            a1 += et[k + 1] * __shfl(v, k + 1, 32);
            a2 += et[k + 2] * __shfl(v, k + 2, 32);
            a3 += et[k + 3] * __shfl(v, k + 3, 32);
        }
        v = ef * ((a0 + a1) + (a2 + a3));
        if ((s & 7) == 7) {       // renorm every 8 steps (incl. final s=127)
            float m = v;
#pragma unroll
            for (int off = 16; off; off >>= 1) m = fmaxf(m, __shfl_xor(m, off, 32));
            if (m > 0.f) { v *= 1.0f / m; sg += __logf(m); }
        }
    }
    QT[(c * 32 + p) * 32 + n] = v;
    if (n == 0) sigma[c * 32 + p] = sg;
}

// ---------------- CRF pass B: sequential chunk combine + final NLL ---------
__global__ void crfB(const float* __restrict__ QT, const float* __restrict__ sigma,
                     const float* __restrict__ trans, const float* __restrict__ gold,
                     float* __restrict__ out) {
    const int lane = threadIdx.x;
    if (lane >= 32) return;
    float alpha = (lane == START_TAG) ? 0.f : NEGV;
    for (int c = 0; c < K_CHUNKS; ++c) {
        const float a = alpha + sigma[c * 32 + lane];   // lane plays role p
        float mu = a;
#pragma unroll
        for (int off = 16; off; off >>= 1) mu = fmaxf(mu, __shfl_xor(mu, off, 32));
        const float w = __expf(a - mu);
        float acc = 0.f;
#pragma unroll
        for (int k = 0; k < 32; ++k)
            acc += QT[(c * 32 + k) * 32 + lane] * __shfl(w, k, 32);
        alpha = (acc > 0.f) ? (__logf(acc) + mu) : -1e30f;
    }
    float tv = alpha + trans[STOP_TAG * 32 + lane];
    float mu2 = tv;
#pragma unroll
    for (int off = 16; off; off >>= 1) mu2 = fmaxf(mu2, __shfl_xor(mu2, off, 32));
    float e = __expf(tv - mu2);
#pragma unroll
    for (int off = 16; off; off >>= 1) e += __shfl_xor(e, off, 32);
    if (lane == 0) out[0] = __logf(e) + mu2 - gold[0];
}

// ---------------- launch ----------------
extern "C" void kernel_launch(void* const* d_in, const int* in_sizes, int n_in,
                              void* d_out, int out_size, void* d_ws, size_t ws_size,
                              hipStream_t stream) {
    const int*   ctx   = (const int*)d_in[0];
    const float* gz    = (const float*)d_in[1];
    const int*   lab   = (const int*)d_in[2];
    const float* emb   = (const float*)d_in[3];
    const float* w1    = (const float*)d_in[4];
    const float* b1    = (const float*)d_in[5];
    const float* w2    = (const float*)d_in[6];
    const float* b2    = (const float*)d_in[7];
    const float* trans = (const float*)d_in[8];
    float* out = (float*)d_out;

    char* ws = (char*)d_ws;
    bf16_t* Xb  = (bf16_t*)(ws + 0);               // 8192*3456*2 = 56,623,104
    bf16_t* W1b = (bf16_t*)(ws + 56623104);        // 1024*3456*2 =  7,077,888
    bf16_t* Hb  = (bf16_t*)(ws + 63700992);        // 8192*1024*2 = 16,777,216
    float*  F   = (float*)(ws + 80478208);         // 8192*32*4   =  1,048,576
    float*  QT  = (float*)(ws + 81526784);         // 64*32*32*4  =    262,144
    float*  sg  = (float*)(ws + 81788928);         // 64*32*4     =      8,192
    float*  gld = (float*)(ws + 81797120);         // 4 bytes

    build_x<<<S_LEN, 256, 0, stream>>>(ctx, gz, emb, Xb);
    build_w1b<<<H_DIM, 256, 0, stream>>>(w1, W1b);
    gemm1<<<dim3(S_LEN / 128, H_DIM / 128), 256, 0, stream>>>(Xb, W1b, b1, Hb);
    feats_k<<<S_LEN / 8, dim3(32, 8), 0, stream>>>(Hb, w2, b2, F);
    gold_k<<<1, 256, 0, stream>>>(F, lab, trans, gld);
    crfA<<<K_CHUNKS * 4, 256, 0, stream>>>(F, trans, QT, sg);
    crfB<<<1, 64, 0, stream>>>(QT, sg, trans, gld, out);
}

// Round 2
// 445.334 us; speedup vs baseline: 1.7534x; 1.7534x over previous
//
#include <hip/hip_runtime.h>

#define S_LEN 8192
#define C_CTX 21
#define E_DIM 128
#define G_DIM 36
#define H_DIM 1024
#define T_TAG 32
#define D_RAW 3444          // 21*(128+36)
#define DP 3456             // padded to multiple of 32 (108 K-iters)
#define START_TAG 30
#define STOP_TAG 31
#define NEGV -10000.0f
#define K_CHUNKS 64
#define L_CHUNK 128         // K_CHUNKS * L_CHUNK == S_LEN

typedef __bf16 bf16_t;
typedef __bf16 bf16x8 __attribute__((ext_vector_type(8)));
typedef float  f32x4  __attribute__((ext_vector_type(4)));

__device__ inline void async_copy16(const bf16_t* g, bf16_t* l) {
    __builtin_amdgcn_global_load_lds(
        (const __attribute__((address_space(1))) void*)g,
        (__attribute__((address_space(3))) void*)l, 16, 0, 0);
}

// ---------------- Phase 0: materialize padded bf16 X and W1 ----------------
__global__ void build_x(const int* __restrict__ ctx, const float* __restrict__ gz,
                        const float* __restrict__ emb, bf16_t* __restrict__ X) {
    const int s = blockIdx.x;
    for (int col = threadIdx.x; col < DP; col += 256) {
        float v = 0.f;
        if (col < D_RAW) {
            const int c = col / 164;
            const int r = col - c * 164;
            if (r < E_DIM) v = emb[(size_t)ctx[s * C_CTX + c] * E_DIM + r];
            else           v = gz[((size_t)s * C_CTX + c) * G_DIM + (r - E_DIM)];
        }
        X[(size_t)s * DP + col] = (bf16_t)v;
    }
}

__global__ void build_w1b(const float* __restrict__ w1, bf16_t* __restrict__ W) {
    const int h = blockIdx.x;
    for (int col = threadIdx.x; col < DP; col += 256)
        W[(size_t)h * DP + col] = (bf16_t)((col < D_RAW) ? w1[(size_t)h * D_RAW + col] : 0.f);
}

// ---------------- Phase 1: h = relu(X @ W1^T + b1), bf16 MFMA -------------
__global__ __launch_bounds__(256) void gemm1(const bf16_t* __restrict__ X,
                                             const bf16_t* __restrict__ W,
                                             const float* __restrict__ b1,
                                             bf16_t* __restrict__ Hout) {
    __shared__ bf16_t As[128 * 32];
    __shared__ bf16_t Bs[128 * 32];
    const int tid  = threadIdx.x;
    const int wave = tid >> 6, lane = tid & 63;
    const int s0 = blockIdx.x * 128, h0 = blockIdx.y * 128;
    const int wm = (wave & 1) * 64, wn = (wave >> 1) * 64;

    const int rowA = tid >> 2, colA = (tid & 3) * 8;
    const bf16_t* gA0 = X + (size_t)(s0 + rowA) * DP + colA;
    const bf16_t* gA1 = X + (size_t)(s0 + rowA + 64) * DP + colA;
    const bf16_t* gB0 = W + (size_t)(h0 + rowA) * DP + colA;
    const bf16_t* gB1 = W + (size_t)(h0 + rowA + 64) * DP + colA;
    bf16_t* lA0 = &As[tid * 8];
    bf16_t* lA1 = &As[(tid + 256) * 8];
    bf16_t* lB0 = &Bs[tid * 8];
    bf16_t* lB1 = &Bs[(tid + 256) * 8];

    const int lrow = lane & 15;
    const int kq   = (lane >> 4) * 8;

    f32x4 acc[4][4] = {};
    for (int k0 = 0; k0 < DP; k0 += 32) {
        async_copy16(gA0 + k0, lA0);
        async_copy16(gA1 + k0, lA1);
        async_copy16(gB0 + k0, lB0);
        async_copy16(gB1 + k0, lB1);
        __syncthreads();
        bf16x8 a[4], b[4];
#pragma unroll
        for (int mt = 0; mt < 4; ++mt)
            a[mt] = *(const bf16x8*)&As[(wm + mt * 16 + lrow) * 32 + kq];
#pragma unroll
        for (int nt = 0; nt < 4; ++nt)
            b[nt] = *(const bf16x8*)&Bs[(wn + nt * 16 + lrow) * 32 + kq];
#pragma unroll
        for (int mt = 0; mt < 4; ++mt)
#pragma unroll
            for (int nt = 0; nt < 4; ++nt)
                acc[mt][nt] = __builtin_amdgcn_mfma_f32_16x16x32_bf16(a[mt], b[nt], acc[mt][nt], 0, 0, 0);
        __syncthreads();
    }
    const int crow = (lane >> 4) * 4;
    const int ccol = lane & 15;
#pragma unroll
    for (int nt = 0; nt < 4; ++nt) {
        const int j = h0 + wn + nt * 16 + ccol;
        const float bv = b1[j];
#pragma unroll
        for (int mt = 0; mt < 4; ++mt) {
#pragma unroll
            for (int r = 0; r < 4; ++r) {
                const int s = s0 + wm + mt * 16 + crow + r;
                const float v = acc[mt][nt][r] + bv;
                Hout[(size_t)s * H_DIM + j] = (bf16_t)fmaxf(v, 0.f);
            }
        }
    }
}

// ---------------- Phase 2: feats = h @ w2^T + b2 (fp32 out) ----------------
__global__ void feats_k(const bf16_t* __restrict__ Hb, const float* __restrict__ w2,
                        const float* __restrict__ b2, float* __restrict__ F) {
    const int t  = threadIdx.x;             // 0..31
    const int sl = threadIdx.y;             // 0..7
    const int s  = blockIdx.x * 8 + sl;
    const bf16_t* hr = Hb + (size_t)s * H_DIM;
    const float*  wr = w2 + t * H_DIM;
    float acc = b2[t];
    for (int j = 0; j < H_DIM; j += 8) {
        bf16x8 hv = *(const bf16x8*)(hr + j);
#pragma unroll
        for (int u = 0; u < 8; ++u) acc += (float)hv[u] * wr[j + u];
    }
    F[(size_t)s * T_TAG + t] = acc;
}

// ---------------- CRF pass A: per-chunk matrix-chain products --------------
// chunk c: P_c = M_{s0+L-1} ... M_{s0}, M_s[n,p] = exp(trans[n,p]+feat_s[n]).
// Stored transposed & column-normalized: QT[c][p][n] = P_c[n][p]*exp(-sigma[c][p]).
__global__ __launch_bounds__(256) void crfA(const float* __restrict__ F,
                                            const float* __restrict__ trans,
                                            float* __restrict__ QT,
                                            float* __restrict__ sigma) {
    __shared__ float fl[L_CHUNK * 32];
    const int c   = blockIdx.x >> 2;
    const int tid = threadIdx.x;
    const int n   = tid & 31;
    const int p   = ((blockIdx.x & 3) << 3) + (tid >> 5);
    const int s0  = c * L_CHUNK;
    for (int i = tid; i < L_CHUNK * 32; i += 256) fl[i] = F[(size_t)s0 * 32 + i];
    __syncthreads();

    float et[32];
#pragma unroll
    for (int k = 0; k < 32; ++k) et[k] = __expf(trans[n * 32 + k]);

    float v  = __expf(trans[n * 32 + p] + fl[n]);
    float sg = 0.f;
    for (int s = 1; s < L_CHUNK; ++s) {
        const float ef = __expf(fl[s * 32 + n]);
        float a0 = 0.f, a1 = 0.f, a2 = 0.f, a3 = 0.f;
#pragma unroll
        for (int k = 0; k < 32; k += 4) {
            a0 += et[k + 0] * __shfl(v, k + 0, 32);
            a1 += et[k + 1] * __shfl(v, k + 1, 32);
            a2 += et[k + 2] * __shfl(v, k + 2, 32);
            a3 += et[k + 3] * __shfl(v, k + 3, 32);
        }
        v = ef * ((a0 + a1) + (a2 + a3));
        if ((s & 7) == 7) {
            float m = v;
#pragma unroll
            for (int off = 16; off; off >>= 1) m = fmaxf(m, __shfl_xor(m, off, 32));
            if (m > 0.f) { v *= 1.0f / m; sg += __logf(m); }
        }
    }
    QT[(c * 32 + p) * 32 + n] = v;
    if (n == 0) sigma[c * 32 + p] = sg;
}

// ---------------- CRF pass B: parallel matrix fold ----------------
// Folds `fold` consecutive chunk matrices (later chunk multiplies on the left):
//   A <- Q_M diag(w) A ; w[k]=exp(sigma_M[k]-max), per-column renorm after.
// blockIdx.x = group index. If final!=0 (grid=1): also gold score + output NLL.
__global__ __launch_bounds__(1024) void crf_fold(const float* __restrict__ Qin,
                                                 const float* __restrict__ Sin,
                                                 const int fold, const int final,
                                                 float* __restrict__ Qout,
                                                 float* __restrict__ Sout,
                                                 const float* __restrict__ trans,
                                                 const float* __restrict__ F,
                                                 const int* __restrict__ lab,
                                                 const float* __restrict__ gunused,
                                                 float* __restrict__ out) {
    __shared__ float A[32][33];
    __shared__ float M[32][33];
    __shared__ float sgf[32];
    __shared__ float gred[16];
    __shared__ float gold_s;

    const int t = threadIdx.x;
    const int p = t >> 5, n = t & 31;
    const int c0 = blockIdx.x * fold;

    // ---- gold score (final kernel only), before the fold ----
    if (final) {
        float ga = 0.f;
        for (int s = t; s < S_LEN; s += 1024) {
            const int tg = lab[s];
            ga += F[(size_t)s * T_TAG + tg];
            const int tp = (s == 0) ? START_TAG : lab[s - 1];
            ga += trans[tg * T_TAG + tp];
        }
        if (t == 0) ga += trans[STOP_TAG * T_TAG + lab[S_LEN - 1]];
#pragma unroll
        for (int off = 32; off; off >>= 1) ga += __shfl_down(ga, off, 64);
        if ((t & 63) == 0) gred[t >> 6] = ga;
    }

    // ---- init accumulator from earliest chunk ----
    A[n][p] = Qin[(size_t)(c0 * 32 + p) * 32 + n];
    float sA = Sin[c0 * 32 + p];
    float mreg = Qin[(size_t)((c0 + 1) * 32 + p) * 32 + n];

    for (int i = 1; i < fold; ++i) {
        // scale of incoming (left) matrix
        const float sMn = Sin[(c0 + i) * 32 + n];
        float mmax = sMn;
#pragma unroll
        for (int off = 16; off; off >>= 1) mmax = fmaxf(mmax, __shfl_xor(mmax, off, 32));
        const float sMp = Sin[(c0 + i) * 32 + p];
        __syncthreads();                       // prior product reads of M done
        M[n][p] = mreg * __expf(sMp - mmax);   // fold column weight into M
        if (i + 1 < fold) mreg = Qin[(size_t)((c0 + i + 1) * 32 + p) * 32 + n];
        __syncthreads();                       // M (and A) visible
        float acc = 0.f;
#pragma unroll 8
        for (int k = 0; k < 32; ++k)
            acc += M[n][k] * A[k][p];          // M: conflict-free (stride 33); A: broadcast
        float cm = acc;
#pragma unroll
        for (int off = 16; off; off >>= 1) cm = fmaxf(cm, __shfl_xor(cm, off, 32));
        cm = fmaxf(cm, 1e-37f);
        __syncthreads();                       // all reads of A done
        A[n][p] = acc / cm;
        sA = sA + mmax + __logf(cm);
    }
    __syncthreads();

    if (!final) {
        Qout[(size_t)(blockIdx.x * 32 + p) * 32 + n] = A[n][p];
        if (n == 0) Sout[blockIdx.x * 32 + p] = sA;
        return;
    }

    // ---- finalize: NLL = sigma[START] + log(sum_n e^{trans[STOP,n]} A[n][START]) - gold
    if (n == 0) sgf[p] = sA;
    if (t == 0) {
        float s = 0.f;
#pragma unroll
        for (int i = 0; i < 16; ++i) s += gred[i];
        gold_s = s;
    }
    __syncthreads();
    if (t < 32) {
        float v = A[t][START_TAG] * __expf(trans[STOP_TAG * T_TAG + t]);
#pragma unroll
        for (int off = 16; off; off >>= 1) v += __shfl_xor(v, off, 32);
        if (t == 0) out[0] = sgf[START_TAG] + __logf(v) - gold_s;
    }
}

// ---------------- launch ----------------
extern "C" void kernel_launch(void* const* d_in, const int* in_sizes, int n_in,
                              void* d_out, int out_size, void* d_ws, size_t ws_size,
                              hipStream_t stream) {
    const int*   ctx   = (const int*)d_in[0];
    const float* gz    = (const float*)d_in[1];
    const int*   lab   = (const int*)d_in[2];
    const float* emb   = (const float*)d_in[3];
    const float* w1    = (const float*)d_in[4];
    const float* b1    = (const float*)d_in[5];
    const float* w2    = (const float*)d_in[6];
    const float* b2    = (const float*)d_in[7];
    const float* trans = (const float*)d_in[8];
    float* out = (float*)d_out;

    char* ws = (char*)d_ws;
    bf16_t* Xb  = (bf16_t*)(ws + 0);               // 8192*3456*2 = 56,623,104
    bf16_t* W1b = (bf16_t*)(ws + 56623104);        // 1024*3456*2 =  7,077,888
    bf16_t* Hb  = (bf16_t*)(ws + 63700992);        // 8192*1024*2 = 16,777,216
    float*  F   = (float*)(ws + 80478208);         // 8192*32*4   =  1,048,576
    float*  QT  = (float*)(ws + 81526784);         // 64*32*32*4  =    262,144
    float*  sg  = (float*)(ws + 81788928);         // 64*32*4     =      8,192
    // fold temporaries overlay the Hb region (Hb fully consumed by feats_k)
    float*  Q1  = (float*)(ws + 63700992);         // 16*32*32*4  =     65,536
    float*  S1  = (float*)(ws + 63766528);         // 16*32*4     =      2,048

    build_x<<<S_LEN, 256, 0, stream>>>(ctx, gz, emb, Xb);
    build_w1b<<<H_DIM, 256, 0, stream>>>(w1, W1b);
    gemm1<<<dim3(S_LEN / 128, H_DIM / 128), 256, 0, stream>>>(Xb, W1b, b1, Hb);
    feats_k<<<S_LEN / 8, dim3(32, 8), 0, stream>>>(Hb, w2, b2, F);
    crfA<<<K_CHUNKS * 4, 256, 0, stream>>>(F, trans, QT, sg);
    crf_fold<<<16, 1024, 0, stream>>>(QT, sg, 4, 0, Q1, S1, trans, F, lab, nullptr, out);
    crf_fold<<<1, 1024, 0, stream>>>(Q1, S1, 16, 1, nullptr, nullptr, trans, F, lab, nullptr, out);
}

// Round 3
// 337.192 us; speedup vs baseline: 2.3158x; 1.3207x over previous
//
#include <hip/hip_runtime.h>

#define S_LEN 8192
#define C_CTX 21
#define E_DIM 128
#define G_DIM 36
#define H_DIM 1024
#define T_TAG 32
#define D_RAW 3444          // 21*(128+36)
#define DP 3456             // padded to multiple of 32 (108 K-iters)
#define START_TAG 30
#define STOP_TAG 31
#define NEGV -10000.0f
#define K_CHUNKS 64
#define L_CHUNK 128         // K_CHUNKS * L_CHUNK == S_LEN

typedef __bf16 bf16_t;
typedef __bf16 bf16x8 __attribute__((ext_vector_type(8)));
typedef float  f32x4  __attribute__((ext_vector_type(4)));

__device__ inline void async_copy16(const bf16_t* g, bf16_t* l) {
    __builtin_amdgcn_global_load_lds(
        (const __attribute__((address_space(1))) void*)g,
        (__attribute__((address_space(3))) void*)l, 16, 0, 0);
}

// ---------------- Phase 0: materialize padded bf16 X and W1 ----------------
__global__ void build_x(const int* __restrict__ ctx, const float* __restrict__ gz,
                        const float* __restrict__ emb, bf16_t* __restrict__ X) {
    const int s = blockIdx.x;
    for (int col = threadIdx.x; col < DP; col += 256) {
        float v = 0.f;
        if (col < D_RAW) {
            const int c = col / 164;
            const int r = col - c * 164;
            if (r < E_DIM) v = emb[(size_t)ctx[s * C_CTX + c] * E_DIM + r];
            else           v = gz[((size_t)s * C_CTX + c) * G_DIM + (r - E_DIM)];
        }
        X[(size_t)s * DP + col] = (bf16_t)v;
    }
}

__global__ void build_w1b(const float* __restrict__ w1, bf16_t* __restrict__ W) {
    const int h = blockIdx.x;
    for (int col = threadIdx.x; col < DP; col += 256)
        W[(size_t)h * DP + col] = (bf16_t)((col < D_RAW) ? w1[(size_t)h * D_RAW + col] : 0.f);
}

__global__ void build_w2b(const float* __restrict__ w2, bf16_t* __restrict__ W) {
    const int i = blockIdx.x * 256 + threadIdx.x;   // 32*1024 total
    W[i] = (bf16_t)w2[i];
}

// ---------------- Phase 1: h = relu(X @ W1^T + b1), bf16 MFMA -------------
__global__ __launch_bounds__(256) void gemm1(const bf16_t* __restrict__ X,
                                             const bf16_t* __restrict__ W,
                                             const float* __restrict__ b1,
                                             bf16_t* __restrict__ Hout) {
    __shared__ bf16_t As[128 * 32];
    __shared__ bf16_t Bs[128 * 32];
    const int tid  = threadIdx.x;
    const int wave = tid >> 6, lane = tid & 63;
    const int s0 = blockIdx.x * 128, h0 = blockIdx.y * 128;
    const int wm = (wave & 1) * 64, wn = (wave >> 1) * 64;

    const int rowA = tid >> 2, colA = (tid & 3) * 8;
    const bf16_t* gA0 = X + (size_t)(s0 + rowA) * DP + colA;
    const bf16_t* gA1 = X + (size_t)(s0 + rowA + 64) * DP + colA;
    const bf16_t* gB0 = W + (size_t)(h0 + rowA) * DP + colA;
    const bf16_t* gB1 = W + (size_t)(h0 + rowA + 64) * DP + colA;
    bf16_t* lA0 = &As[tid * 8];
    bf16_t* lA1 = &As[(tid + 256) * 8];
    bf16_t* lB0 = &Bs[tid * 8];
    bf16_t* lB1 = &Bs[(tid + 256) * 8];

    const int lrow = lane & 15;
    const int kq   = (lane >> 4) * 8;

    f32x4 acc[4][4] = {};
    for (int k0 = 0; k0 < DP; k0 += 32) {
        async_copy16(gA0 + k0, lA0);
        async_copy16(gA1 + k0, lA1);
        async_copy16(gB0 + k0, lB0);
        async_copy16(gB1 + k0, lB1);
        __syncthreads();
        bf16x8 a[4], b[4];
#pragma unroll
        for (int mt = 0; mt < 4; ++mt)
            a[mt] = *(const bf16x8*)&As[(wm + mt * 16 + lrow) * 32 + kq];
#pragma unroll
        for (int nt = 0; nt < 4; ++nt)
            b[nt] = *(const bf16x8*)&Bs[(wn + nt * 16 + lrow) * 32 + kq];
#pragma unroll
        for (int mt = 0; mt < 4; ++mt)
#pragma unroll
            for (int nt = 0; nt < 4; ++nt)
                acc[mt][nt] = __builtin_amdgcn_mfma_f32_16x16x32_bf16(a[mt], b[nt], acc[mt][nt], 0, 0, 0);
        __syncthreads();
    }
    const int crow = (lane >> 4) * 4;
    const int ccol = lane & 15;
#pragma unroll
    for (int nt = 0; nt < 4; ++nt) {
        const int j = h0 + wn + nt * 16 + ccol;
        const float bv = b1[j];
#pragma unroll
        for (int mt = 0; mt < 4; ++mt) {
#pragma unroll
            for (int r = 0; r < 4; ++r) {
                const int s = s0 + wm + mt * 16 + crow + r;
                const float v = acc[mt][nt][r] + bv;
                Hout[(size_t)s * H_DIM + j] = (bf16_t)fmaxf(v, 0.f);
            }
        }
    }
}

// ---------------- Phase 2: feats = H @ w2^T + b2 (fp32 out), MFMA ----------
// M=128 (seq) x N=32 (tags), K=1024 in steps of 32. 4 waves, each 32x32 out.
__global__ __launch_bounds__(256) void feats_mfma(const bf16_t* __restrict__ Hb,
                                                  const bf16_t* __restrict__ W2b,
                                                  const float* __restrict__ b2,
                                                  float* __restrict__ F) {
    __shared__ bf16_t As[128 * 32];
    __shared__ bf16_t Bs[32 * 32];
    const int tid  = threadIdx.x;
    const int wave = tid >> 6, lane = tid & 63;
    const int s0 = blockIdx.x * 128;
    const int wm = wave * 32;

    const int rowA = tid >> 2, colA = (tid & 3) * 8;
    const bf16_t* gA0 = Hb + (size_t)(s0 + rowA) * H_DIM + colA;
    const bf16_t* gA1 = Hb + (size_t)(s0 + rowA + 64) * H_DIM + colA;
    const bf16_t* gB  = W2b + (size_t)rowA * H_DIM + colA;   // valid for tid<128
    bf16_t* lA0 = &As[tid * 8];
    bf16_t* lA1 = &As[(tid + 256) * 8];
    bf16_t* lB  = &Bs[tid * 8];

    const int lrow = lane & 15;
    const int kq   = (lane >> 4) * 8;

    f32x4 acc[2][2] = {};
    for (int k0 = 0; k0 < H_DIM; k0 += 32) {
        async_copy16(gA0 + k0, lA0);
        async_copy16(gA1 + k0, lA1);
        if (tid < 128) async_copy16(gB + k0, lB);
        __syncthreads();
        bf16x8 a[2], b[2];
#pragma unroll
        for (int mt = 0; mt < 2; ++mt)
            a[mt] = *(const bf16x8*)&As[(wm + mt * 16 + lrow) * 32 + kq];
#pragma unroll
        for (int nt = 0; nt < 2; ++nt)
            b[nt] = *(const bf16x8*)&Bs[(nt * 16 + lrow) * 32 + kq];
#pragma unroll
        for (int mt = 0; mt < 2; ++mt)
#pragma unroll
            for (int nt = 0; nt < 2; ++nt)
                acc[mt][nt] = __builtin_amdgcn_mfma_f32_16x16x32_bf16(a[mt], b[nt], acc[mt][nt], 0, 0, 0);
        __syncthreads();
    }
    const int crow = (lane >> 4) * 4;
    const int ccol = lane & 15;
#pragma unroll
    for (int nt = 0; nt < 2; ++nt) {
        const int j = nt * 16 + ccol;
        const float bv = b2[j];
#pragma unroll
        for (int mt = 0; mt < 2; ++mt) {
#pragma unroll
            for (int r = 0; r < 4; ++r) {
                const int s = s0 + wm + mt * 16 + crow + r;
                F[(size_t)s * T_TAG + j] = acc[mt][nt][r] + bv;
            }
        }
    }
}

// ---------------- CRF pass A: per-chunk matrix-chain products --------------
__global__ __launch_bounds__(256) void crfA(const float* __restrict__ F,
                                            const float* __restrict__ trans,
                                            float* __restrict__ QT,
                                            float* __restrict__ sigma) {
    __shared__ float fl[L_CHUNK * 32];
    const int c   = blockIdx.x >> 2;
    const int tid = threadIdx.x;
    const int n   = tid & 31;
    const int p   = ((blockIdx.x & 3) << 3) + (tid >> 5);
    const int s0  = c * L_CHUNK;
    for (int i = tid; i < L_CHUNK * 32; i += 256) fl[i] = F[(size_t)s0 * 32 + i];
    __syncthreads();

    float et[32];
#pragma unroll
    for (int k = 0; k < 32; ++k) et[k] = __expf(trans[n * 32 + k]);

    float v  = __expf(trans[n * 32 + p] + fl[n]);
    float sg = 0.f;
    for (int s = 1; s < L_CHUNK; ++s) {
        const float ef = __expf(fl[s * 32 + n]);
        float a0 = 0.f, a1 = 0.f, a2 = 0.f, a3 = 0.f;
#pragma unroll
        for (int k = 0; k < 32; k += 4) {
            a0 += et[k + 0] * __shfl(v, k + 0, 32);
            a1 += et[k + 1] * __shfl(v, k + 1, 32);
            a2 += et[k + 2] * __shfl(v, k + 2, 32);
            a3 += et[k + 3] * __shfl(v, k + 3, 32);
        }
        v = ef * ((a0 + a1) + (a2 + a3));
        if ((s & 7) == 7) {
            float m = v;
#pragma unroll
            for (int off = 16; off; off >>= 1) m = fmaxf(m, __shfl_xor(m, off, 32));
            if (m > 0.f) { v *= 1.0f / m; sg += __logf(m); }
        }
    }
    QT[(c * 32 + p) * 32 + n] = v;
    if (n == 0) sigma[c * 32 + p] = sg;
}

// ---------------- CRF pass B: parallel matrix fold ----------------
__global__ __launch_bounds__(1024) void crf_fold(const float* __restrict__ Qin,
                                                 const float* __restrict__ Sin,
                                                 const int fold, const int final,
                                                 float* __restrict__ Qout,
                                                 float* __restrict__ Sout,
                                                 const float* __restrict__ trans,
                                                 const float* __restrict__ F,
                                                 const int* __restrict__ lab,
                                                 float* __restrict__ out) {
    __shared__ float A[32][33];
    __shared__ float M[32][33];
    __shared__ float sgf[32];
    __shared__ float gred[16];
    __shared__ float gold_s;

    const int t = threadIdx.x;
    const int p = t >> 5, n = t & 31;
    const int c0 = blockIdx.x * fold;

    if (final) {
        float ga = 0.f;
        for (int s = t; s < S_LEN; s += 1024) {
            const int tg = lab[s];
            ga += F[(size_t)s * T_TAG + tg];
            const int tp = (s == 0) ? START_TAG : lab[s - 1];
            ga += trans[tg * T_TAG + tp];
        }
        if (t == 0) ga += trans[STOP_TAG * T_TAG + lab[S_LEN - 1]];
#pragma unroll
        for (int off = 32; off; off >>= 1) ga += __shfl_down(ga, off, 64);
        if ((t & 63) == 0) gred[t >> 6] = ga;
    }

    A[n][p] = Qin[(size_t)(c0 * 32 + p) * 32 + n];
    float sA = Sin[c0 * 32 + p];
    float mreg = Qin[(size_t)((c0 + 1) * 32 + p) * 32 + n];

    for (int i = 1; i < fold; ++i) {
        const float sMn = Sin[(c0 + i) * 32 + n];
        float mmax = sMn;
#pragma unroll
        for (int off = 16; off; off >>= 1) mmax = fmaxf(mmax, __shfl_xor(mmax, off, 32));
        const float sMp = Sin[(c0 + i) * 32 + p];
        __syncthreads();
        M[n][p] = mreg * __expf(sMp - mmax);
        if (i + 1 < fold) mreg = Qin[(size_t)((c0 + i + 1) * 32 + p) * 32 + n];
        __syncthreads();
        float acc = 0.f;
#pragma unroll 8
        for (int k = 0; k < 32; ++k)
            acc += M[n][k] * A[k][p];
        float cm = acc;
#pragma unroll
        for (int off = 16; off; off >>= 1) cm = fmaxf(cm, __shfl_xor(cm, off, 32));
        cm = fmaxf(cm, 1e-37f);
        __syncthreads();
        A[n][p] = acc / cm;
        sA = sA + mmax + __logf(cm);
    }
    __syncthreads();

    if (!final) {
        Qout[(size_t)(blockIdx.x * 32 + p) * 32 + n] = A[n][p];
        if (n == 0) Sout[blockIdx.x * 32 + p] = sA;
        return;
    }

    if (n == 0) sgf[p] = sA;
    if (t == 0) {
        float s = 0.f;
#pragma unroll
        for (int i = 0; i < 16; ++i) s += gred[i];
        gold_s = s;
    }
    __syncthreads();
    if (t < 32) {
        float v = A[t][START_TAG] * __expf(trans[STOP_TAG * T_TAG + t]);
#pragma unroll
        for (int off = 16; off; off >>= 1) v += __shfl_xor(v, off, 32);
        if (t == 0) out[0] = sgf[START_TAG] + __logf(v) - gold_s;
    }
}

// ---------------- launch ----------------
extern "C" void kernel_launch(void* const* d_in, const int* in_sizes, int n_in,
                              void* d_out, int out_size, void* d_ws, size_t ws_size,
                              hipStream_t stream) {
    const int*   ctx   = (const int*)d_in[0];
    const float* gz    = (const float*)d_in[1];
    const int*   lab   = (const int*)d_in[2];
    const float* emb   = (const float*)d_in[3];
    const float* w1    = (const float*)d_in[4];
    const float* b1    = (const float*)d_in[5];
    const float* w2    = (const float*)d_in[6];
    const float* b2    = (const float*)d_in[7];
    const float* trans = (const float*)d_in[8];
    float* out = (float*)d_out;

    char* ws = (char*)d_ws;
    bf16_t* Xb  = (bf16_t*)(ws + 0);               // 8192*3456*2 = 56,623,104
    bf16_t* W1b = (bf16_t*)(ws + 56623104);        // 1024*3456*2 =  7,077,888
    bf16_t* Hb  = (bf16_t*)(ws + 63700992);        // 8192*1024*2 = 16,777,216
    float*  F   = (float*)(ws + 80478208);         // 8192*32*4   =  1,048,576
    float*  QT  = (float*)(ws + 81526784);         // 64*32*32*4  =    262,144
    float*  sg  = (float*)(ws + 81788928);         // 64*32*4     =      8,192
    // overlays of the Xb region (Xb fully consumed once gemm1 completes):
    bf16_t* W2b = (bf16_t*)(ws + 0);               // 32*1024*2   =     65,536
    float*  Q1  = (float*)(ws + 65536);            // 16*32*32*4  =     65,536
    float*  S1  = (float*)(ws + 131072);           // 16*32*4     =      2,048

    build_x<<<S_LEN, 256, 0, stream>>>(ctx, gz, emb, Xb);
    build_w1b<<<H_DIM, 256, 0, stream>>>(w1, W1b);
    gemm1<<<dim3(S_LEN / 128, H_DIM / 128), 256, 0, stream>>>(Xb, W1b, b1, Hb);
    build_w2b<<<(T_TAG * H_DIM) / 256, 256, 0, stream>>>(w2, W2b);   // after gemm1 (overlays Xb)
    feats_mfma<<<S_LEN / 128, 256, 0, stream>>>(Hb, W2b, b2, F);
    crfA<<<K_CHUNKS * 4, 256, 0, stream>>>(F, trans, QT, sg);
    crf_fold<<<16, 1024, 0, stream>>>(QT, sg, 4, 0, Q1, S1, trans, F, lab, out);
    crf_fold<<<1, 1024, 0, stream>>>(Q1, S1, 16, 1, nullptr, nullptr, trans, F, lab, out);
}

// Round 5
// 289.047 us; speedup vs baseline: 2.7015x; 1.1666x over previous
//
#include <hip/hip_runtime.h>

#define S_LEN 8192
#define C_CTX 21
#define E_DIM 128
#define G_DIM 36
#define H_DIM 1024
#define T_TAG 32
#define D_RAW 3444          // 21*(128+36)
#define DP 3456             // padded to multiple of 32 (108 K-iters)
#define START_TAG 30
#define STOP_TAG 31
#define NEGV -10000.0f
#define K_CHUNKS 64
#define L_CHUNK 128         // K_CHUNKS * L_CHUNK == S_LEN

typedef __bf16 bf16_t;
typedef __bf16 bf16x4 __attribute__((ext_vector_type(4)));
typedef __bf16 bf16x8 __attribute__((ext_vector_type(8)));
typedef float  f32x4  __attribute__((ext_vector_type(4)));

__device__ inline void async_copy16(const bf16_t* g, bf16_t* l) {
    __builtin_amdgcn_global_load_lds(
        (const __attribute__((address_space(1))) void*)g,
        (__attribute__((address_space(3))) void*)l, 16, 0, 0);
}

// ---------------- Phase 0: materialize padded bf16 X and W1 ----------------
// 4 cols per thread: 164 = 41 groups of 4; groups never straddle emb/gz.
__global__ void build_x(const int* __restrict__ ctx, const float* __restrict__ gz,
                        const float* __restrict__ emb, bf16_t* __restrict__ X) {
    const int s = blockIdx.x;
    for (int g = threadIdx.x; g < DP / 4; g += 256) {   // 864 groups
        float4 v = {0.f, 0.f, 0.f, 0.f};
        if (g < D_RAW / 4) {                             // 861 real groups
            const int c  = g / 41;
            const int rg = g - c * 41;                   // 0..40
            if (rg < 32) v = *(const float4*)&emb[(size_t)ctx[s * C_CTX + c] * E_DIM + rg * 4];
            else         v = *(const float4*)&gz[((size_t)s * C_CTX + c) * G_DIM + (rg - 32) * 4];
        }
        bf16x4 o = {(bf16_t)v.x, (bf16_t)v.y, (bf16_t)v.z, (bf16_t)v.w};
        *(bf16x4*)&X[(size_t)s * DP + g * 4] = o;
    }
}

__global__ void build_w1b(const float* __restrict__ w1, bf16_t* __restrict__ W) {
    const int h = blockIdx.x;
    for (int g = threadIdx.x; g < DP / 4; g += 256) {
        float4 v = {0.f, 0.f, 0.f, 0.f};
        if (g < D_RAW / 4) v = *(const float4*)&w1[(size_t)h * D_RAW + g * 4];
        bf16x4 o = {(bf16_t)v.x, (bf16_t)v.y, (bf16_t)v.z, (bf16_t)v.w};
        *(bf16x4*)&W[(size_t)h * DP + g * 4] = o;
    }
}

// ---------------- Phase 1: h = relu(X @ W1^T + b1), bf16 MFMA -------------
// 128x128 tile. LDS k-group swizzle kg^( (row>>1)&3 ): conflict-free ds_read_b128.
__global__ __launch_bounds__(256) void gemm1(const bf16_t* __restrict__ X,
                                             const bf16_t* __restrict__ W,
                                             const float* __restrict__ b1,
                                             bf16_t* __restrict__ Hout) {
    __shared__ bf16_t As[128 * 32];
    __shared__ bf16_t Bs[128 * 32];
    const int tid  = threadIdx.x;
    const int wave = tid >> 6, lane = tid & 63;
    const int s0 = blockIdx.x * 128, h0 = blockIdx.y * 128;
    const int wm = (wave & 1) * 64, wn = (wave >> 1) * 64;

    const int rowA = tid >> 2;
    const int kgs  = (tid & 3) ^ ((rowA >> 1) & 3);   // swizzled source k-group
    const int colA = kgs * 8;
    const bf16_t* gA0 = X + (size_t)(s0 + rowA) * DP + colA;
    const bf16_t* gA1 = X + (size_t)(s0 + rowA + 64) * DP + colA;   // (row+64)>>1 ≡ row>>1 (mod 4)
    const bf16_t* gB0 = W + (size_t)(h0 + rowA) * DP + colA;
    const bf16_t* gB1 = W + (size_t)(h0 + rowA + 64) * DP + colA;
    bf16_t* lA0 = &As[tid * 8];
    bf16_t* lA1 = &As[(tid + 256) * 8];
    bf16_t* lB0 = &Bs[tid * 8];
    bf16_t* lB1 = &Bs[(tid + 256) * 8];

    const int lrow = lane & 15;
    const int kq   = ((lane >> 4) ^ ((lrow >> 1) & 3)) * 8;   // swizzled read offset

    f32x4 acc[4][4] = {};
    for (int k0 = 0; k0 < DP; k0 += 32) {
        async_copy16(gA0 + k0, lA0);
        async_copy16(gA1 + k0, lA1);
        async_copy16(gB0 + k0, lB0);
        async_copy16(gB1 + k0, lB1);
        __syncthreads();
        bf16x8 a[4], b[4];
#pragma unroll
        for (int mt = 0; mt < 4; ++mt)
            a[mt] = *(const bf16x8*)&As[(wm + mt * 16 + lrow) * 32 + kq];
#pragma unroll
        for (int nt = 0; nt < 4; ++nt)
            b[nt] = *(const bf16x8*)&Bs[(wn + nt * 16 + lrow) * 32 + kq];
#pragma unroll
        for (int mt = 0; mt < 4; ++mt)
#pragma unroll
            for (int nt = 0; nt < 4; ++nt)
                acc[mt][nt] = __builtin_amdgcn_mfma_f32_16x16x32_bf16(a[mt], b[nt], acc[mt][nt], 0, 0, 0);
        __syncthreads();
    }
    const int crow = (lane >> 4) * 4;
    const int ccol = lane & 15;
#pragma unroll
    for (int nt = 0; nt < 4; ++nt) {
        const int j = h0 + wn + nt * 16 + ccol;
        const float bv = b1[j];
#pragma unroll
        for (int mt = 0; mt < 4; ++mt) {
#pragma unroll
            for (int r = 0; r < 4; ++r) {
                const int s = s0 + wm + mt * 16 + crow + r;
                const float v = acc[mt][nt][r] + bv;
                Hout[(size_t)s * H_DIM + j] = (bf16_t)fmaxf(v, 0.f);
            }
        }
    }
}

// ---------------- Phase 2: feats = H @ w2^T + b2 (fp32 out), MFMA ----------
// M=128 x N=32, BK=64 (16 iters). A via global_load_lds; B converted fp32->bf16
// in-kernel. 64-wide rows: swizzle kg ^ (row&7).
__global__ __launch_bounds__(256) void feats_mfma(const bf16_t* __restrict__ Hb,
                                                  const float* __restrict__ w2,
                                                  const float* __restrict__ b2,
                                                  float* __restrict__ F) {
    __shared__ bf16_t As[128 * 64];
    __shared__ bf16_t Bs[32 * 64];
    const int tid  = threadIdx.x;
    const int wave = tid >> 6, lane = tid & 63;
    const int s0 = blockIdx.x * 128;
    const int wm = wave * 32;

    // A staging: chunk i*256+tid -> row = i*32 + (tid>>3), kg = tid&7
    const int arow = tid >> 3;
    const int akgs = (tid & 7) ^ (arow & 7);          // (i*32+arow)&7 == arow&7
    const bf16_t* gA = Hb + (size_t)(s0 + arow) * H_DIM + akgs * 8;
    // B staging: row = tid>>3 (0..31), kg = tid&7
    const int brow = tid >> 3;
    const int bkgs = (tid & 7) ^ (brow & 7);
    const float* wp = w2 + (size_t)brow * H_DIM + bkgs * 8;
    bf16_t* lB = &Bs[tid * 8];

    const int lrow = lane & 15;

    f32x4 acc[2][2] = {};
    for (int k0 = 0; k0 < H_DIM; k0 += 64) {
#pragma unroll
        for (int i = 0; i < 4; ++i)
            async_copy16(gA + (size_t)i * 32 * H_DIM + k0, &As[(tid + i * 256) * 8]);
        const float4 x0 = *(const float4*)(wp + k0);
        const float4 x1 = *(const float4*)(wp + k0 + 4);
        bf16x8 bb = {(bf16_t)x0.x, (bf16_t)x0.y, (bf16_t)x0.z, (bf16_t)x0.w,
                     (bf16_t)x1.x, (bf16_t)x1.y, (bf16_t)x1.z, (bf16_t)x1.w};
        *(bf16x8*)lB = bb;
        __syncthreads();
#pragma unroll
        for (int ks = 0; ks < 2; ++ks) {
            const int kq = ((ks * 4 + (lane >> 4)) ^ (lrow & 7)) * 8;
            bf16x8 a[2], b[2];
#pragma unroll
            for (int mt = 0; mt < 2; ++mt)
                a[mt] = *(const bf16x8*)&As[(wm + mt * 16 + lrow) * 64 + kq];
#pragma unroll
            for (int nt = 0; nt < 2; ++nt)
                b[nt] = *(const bf16x8*)&Bs[(nt * 16 + lrow) * 64 + kq];
#pragma unroll
            for (int mt = 0; mt < 2; ++mt)
#pragma unroll
                for (int nt = 0; nt < 2; ++nt)
                    acc[mt][nt] = __builtin_amdgcn_mfma_f32_16x16x32_bf16(a[mt], b[nt], acc[mt][nt], 0, 0, 0);
        }
        __syncthreads();
    }
    const int crow = (lane >> 4) * 4;
    const int ccol = lane & 15;
#pragma unroll
    for (int nt = 0; nt < 2; ++nt) {
        const int j = nt * 16 + ccol;
        const float bv = b2[j];
#pragma unroll
        for (int mt = 0; mt < 2; ++mt) {
#pragma unroll
            for (int r = 0; r < 4; ++r) {
                const int s = s0 + wm + mt * 16 + crow + r;
                F[(size_t)s * T_TAG + j] = acc[mt][nt][r] + bv;
            }
        }
    }
}

// ---------------- CRF pass A: per-chunk matrix-chain products --------------
// v round-trips through a per-wave LDS slice (wave-lockstep => barrier-free):
// 1 ds_write + 8 broadcast ds_read_b128 per step instead of 32 bpermutes.
__global__ __launch_bounds__(256) void crfA(const float* __restrict__ F,
                                            const float* __restrict__ trans,
                                            float* __restrict__ QT,
                                            float* __restrict__ sigma) {
    __shared__ float fl[L_CHUNK * 32];
    __shared__ float vb[4][2][32];
    const int c    = blockIdx.x >> 2;
    const int tid  = threadIdx.x;
    const int wave = tid >> 6;
    const int lane = tid & 63;
    const int n    = lane & 31;
    const int pl   = lane >> 5;
    const int p    = ((blockIdx.x & 3) << 3) + (wave << 1) + pl;
    const int s0   = c * L_CHUNK;
    for (int i = tid; i < L_CHUNK * 32; i += 256) fl[i] = F[(size_t)s0 * 32 + i];
    __syncthreads();

    float et[32];
#pragma unroll
    for (int k = 0; k < 32; ++k) et[k] = __expf(trans[n * 32 + k]);

    float* vrow = &vb[wave][pl][0];
    float v  = __expf(trans[n * 32 + p] + fl[n]);
    float sg = 0.f;
    for (int s = 1; s < L_CHUNK; ++s) {
        vrow[n] = v;
        __builtin_amdgcn_s_waitcnt(0xC07F);   // lgkmcnt(0): wave-coherent LDS
        float a0 = 0.f, a1 = 0.f, a2 = 0.f, a3 = 0.f;
#pragma unroll
        for (int q = 0; q < 8; ++q) {
            const float4 wv = *(const float4*)&vrow[q * 4];
            a0 = __builtin_fmaf(et[q * 4 + 0], wv.x, a0);
            a1 = __builtin_fmaf(et[q * 4 + 1], wv.y, a1);
            a2 = __builtin_fmaf(et[q * 4 + 2], wv.z, a2);
            a3 = __builtin_fmaf(et[q * 4 + 3], wv.w, a3);
        }
        v = __expf(fl[s * 32 + n]) * ((a0 + a1) + (a2 + a3));
        if ((s & 7) == 7) {
            float m = v;
#pragma unroll
            for (int off = 16; off; off >>= 1) m = fmaxf(m, __shfl_xor(m, off, 32));
            if (m > 0.f) { v *= 1.0f / m; sg += __logf(m); }
        }
    }
    QT[(c * 32 + p) * 32 + n] = v;
    if (n == 0) sigma[c * 32 + p] = sg;
}

// ---------------- CRF pass B: parallel matrix fold ----------------
__global__ __launch_bounds__(1024) void crf_fold(const float* __restrict__ Qin,
                                                 const float* __restrict__ Sin,
                                                 const int fold, const int final,
                                                 float* __restrict__ Qout,
                                                 float* __restrict__ Sout,
                                                 const float* __restrict__ trans,
                                                 const float* __restrict__ F,
                                                 const int* __restrict__ lab,
                                                 float* __restrict__ out) {
    __shared__ float A[32][33];
    __shared__ float M[32][33];
    __shared__ float sgf[32];
    __shared__ float gred[16];
    __shared__ float gold_s;

    const int t = threadIdx.x;
    const int p = t >> 5, n = t & 31;
    const int c0 = blockIdx.x * fold;

    if (final) {
        float ga = 0.f;
        for (int s = t; s < S_LEN; s += 1024) {
            const int tg = lab[s];
            ga += F[(size_t)s * T_TAG + tg];
            const int tp = (s == 0) ? START_TAG : lab[s - 1];
            ga += trans[tg * T_TAG + tp];
        }
        if (t == 0) ga += trans[STOP_TAG * T_TAG + lab[S_LEN - 1]];
#pragma unroll
        for (int off = 32; off; off >>= 1) ga += __shfl_down(ga, off, 64);
        if ((t & 63) == 0) gred[t >> 6] = ga;
    }

    A[n][p] = Qin[(size_t)(c0 * 32 + p) * 32 + n];
    float sA = Sin[c0 * 32 + p];
    float mreg = Qin[(size_t)((c0 + 1) * 32 + p) * 32 + n];

    for (int i = 1; i < fold; ++i) {
        const float sMn = Sin[(c0 + i) * 32 + n];
        float mmax = sMn;
#pragma unroll
        for (int off = 16; off; off >>= 1) mmax = fmaxf(mmax, __shfl_xor(mmax, off, 32));
        const float sMp = Sin[(c0 + i) * 32 + p];
        __syncthreads();
        M[n][p] = mreg * __expf(sMp - mmax);
        if (i + 1 < fold) mreg = Qin[(size_t)((c0 + i + 1) * 32 + p) * 32 + n];
        __syncthreads();
        float acc = 0.f;
#pragma unroll 8
        for (int k = 0; k < 32; ++k)
            acc += M[n][k] * A[k][p];
        float cm = acc;
#pragma unroll
        for (int off = 16; off; off >>= 1) cm = fmaxf(cm, __shfl_xor(cm, off, 32));
        cm = fmaxf(cm, 1e-37f);
        __syncthreads();
        A[n][p] = acc / cm;
        sA = sA + mmax + __logf(cm);
    }
    __syncthreads();

    if (!final) {
        Qout[(size_t)(blockIdx.x * 32 + p) * 32 + n] = A[n][p];
        if (n == 0) Sout[blockIdx.x * 32 + p] = sA;
        return;
    }

    if (n == 0) sgf[p] = sA;
    if (t == 0) {
        float s = 0.f;
#pragma unroll
        for (int i = 0; i < 16; ++i) s += gred[i];
        gold_s = s;
    }
    __syncthreads();
    if (t < 32) {
        float v = A[t][START_TAG] * __expf(trans[STOP_TAG * T_TAG + t]);
#pragma unroll
        for (int off = 16; off; off >>= 1) v += __shfl_xor(v, off, 32);
        if (t == 0) out[0] = sgf[START_TAG] + __logf(v) - gold_s;
    }
}

// ---------------- launch ----------------
extern "C" void kernel_launch(void* const* d_in, const int* in_sizes, int n_in,
                              void* d_out, int out_size, void* d_ws, size_t ws_size,
                              hipStream_t stream) {
    const int*   ctx   = (const int*)d_in[0];
    const float* gz    = (const float*)d_in[1];
    const int*   lab   = (const int*)d_in[2];
    const float* emb   = (const float*)d_in[3];
    const float* w1    = (const float*)d_in[4];
    const float* b1    = (const float*)d_in[5];
    const float* w2    = (const float*)d_in[6];
    const float* b2    = (const float*)d_in[7];
    const float* trans = (const float*)d_in[8];
    float* out = (float*)d_out;

    char* ws = (char*)d_ws;
    bf16_t* Xb  = (bf16_t*)(ws + 0);               // 8192*3456*2 = 56,623,104
    bf16_t* W1b = (bf16_t*)(ws + 56623104);        // 1024*3456*2 =  7,077,888
    bf16_t* Hb  = (bf16_t*)(ws + 63700992);        // 8192*1024*2 = 16,777,216
    float*  F   = (float*)(ws + 80478208);         // 8192*32*4   =  1,048,576
    float*  QT  = (float*)(ws + 81526784);         // 64*32*32*4  =    262,144
    float*  sg  = (float*)(ws + 81788928);         // 64*32*4     =      8,192
    // fold temporaries overlay the Xb region (consumed after gemm1):
    float*  Q1  = (float*)(ws + 65536);            // 16*32*32*4  =     65,536
    float*  S1  = (float*)(ws + 131072);           // 16*32*4     =      2,048

    build_x<<<S_LEN, 256, 0, stream>>>(ctx, gz, emb, Xb);
    build_w1b<<<H_DIM, 256, 0, stream>>>(w1, W1b);
    gemm1<<<dim3(S_LEN / 128, H_DIM / 128), 256, 0, stream>>>(Xb, W1b, b1, Hb);
    feats_mfma<<<S_LEN / 128, 256, 0, stream>>>(Hb, w2, b2, F);
    crfA<<<K_CHUNKS * 4, 256, 0, stream>>>(F, trans, QT, sg);
    crf_fold<<<16, 1024, 0, stream>>>(QT, sg, 4, 0, Q1, S1, trans, F, lab, out);
    crf_fold<<<1, 1024, 0, stream>>>(Q1, S1, 16, 1, nullptr, nullptr, trans, F, lab, out);
}